// Round 1
// baseline (145.438 us; speedup 1.0000x reference)
//
#include <hip/hip_runtime.h>

#define M_B   8192
#define K_IN  784
#define KPAD  832          // 13 tiles of 64
#define N_H   4096
#define N_OUT 10
#define TILES 13

typedef __attribute__((ext_vector_type(8))) short bf16x8;
typedef __attribute__((ext_vector_type(4))) float f32x4;
typedef unsigned short u16;
typedef unsigned int   u32;

__device__ __forceinline__ u16 f2bf(float f) {
    union { float f; u32 u; } v; v.f = f;
    u32 r = (v.u + 0x7fffu + ((v.u >> 16) & 1u)) >> 16;
    return (u16)r;
}
__device__ __forceinline__ void load_lds16(const void* g, void* l) {
    __builtin_amdgcn_global_load_lds(
        (const __attribute__((address_space(1))) void*)g,
        (__attribute__((address_space(3))) void*)l, 16, 0, 0);
}

// ---- merged prep: x->bf16[8192][832], w1->tern bf16[4096][832],
//      w2->tern int8[4096][16], plog<-0 ----
__global__ void prep_all(const float* __restrict__ x, const float* __restrict__ w1,
                         const float* __restrict__ w2,
                         u16* __restrict__ xb, u16* __restrict__ w1b,
                         signed char* __restrict__ w2c, float* __restrict__ plog) {
    const int blk = blockIdx.x;
    const int tid = threadIdx.x;
    if (blk < 3328) {                       // ---- x: 8192*104 chunks ----
        int idx = blk * 256 + tid;
        int row = idx / 104;
        int col = (idx - row * 104) * 8;
        u16 v[8];
        if (col < K_IN) {
            const float4* p = (const float4*)(x + (size_t)row * K_IN + col);
            float4 a = p[0], b = p[1];
            v[0] = f2bf(a.x); v[1] = f2bf(a.y); v[2] = f2bf(a.z); v[3] = f2bf(a.w);
            v[4] = f2bf(b.x); v[5] = f2bf(b.y); v[6] = f2bf(b.z); v[7] = f2bf(b.w);
        } else {
            #pragma unroll
            for (int i = 0; i < 8; ++i) v[i] = 0;
        }
        *(uint4*)(xb + (size_t)row * KPAD + col) = *(const uint4*)v;
    } else if (blk < 4992) {                // ---- w1 ternary: 4096*104 ----
        int idx = (blk - 3328) * 256 + tid;
        int row = idx / 104;
        int col = (idx - row * 104) * 8;
        u16 v[8];
        if (col < K_IN) {
            const float4* p = (const float4*)(w1 + (size_t)row * K_IN + col);
            float4 a = p[0], b = p[1];
            float ff[8] = {a.x, a.y, a.z, a.w, b.x, b.y, b.z, b.w};
            #pragma unroll
            for (int i = 0; i < 8; ++i)
                v[i] = ff[i] > 0.1f ? 0x3F80u : (ff[i] < -0.1f ? 0xBF80u : 0u);
        } else {
            #pragma unroll
            for (int i = 0; i < 8; ++i) v[i] = 0;
        }
        *(uint4*)(w1b + (size_t)row * KPAD + col) = *(const uint4*)v;
    } else if (blk < 5008) {                // ---- w2 ternary int8, k-major ----
        int k = (blk - 4992) * 256 + tid;
        if (k >= N_H) return;
        signed char v[16];
        #pragma unroll
        for (int o = 0; o < 16; ++o) v[o] = 0;
        #pragma unroll
        for (int o = 0; o < N_OUT; ++o) {
            float f = w2[(size_t)o * N_H + k];
            v[o] = f > 0.1f ? 1 : (f < -0.1f ? -1 : 0);
        }
        *(int4*)(w2c + (size_t)k * 16) = *(const int4*)v;
    } else {                                // ---- zero plog [8192][16] f32 ----
        int idx = (blk - 5008) * 256 + tid;      // 32768 uint4s
        ((uint4*)plog)[idx] = make_uint4(0, 0, 0, 0);
    }
}

// =====================================================================
// 256x256 8-phase pipelined GEMM (T2+T3+T4+T5), fused w2 epilogue.
//
// Tiles: BM=256 (j), BN=256 (b), BK=64, 512 thr = 8 waves (2 j x 4 b),
// wave tile 128(j) x 64(b). LDS = 128 KB: op(A,B) x buf(2) x khalf(2)
// x [256 rows][32 cols] bf16 regions of 16 KB.
//
// Swizzle (both-sides): region slot (row, c2) holds global k-chunk
// co = c2 ^ ((row>>1)&3). Frag reads then hit all 8 mod-128B slots
// per 16-lane quarter -> zero bank conflict. global_load_lds dest is
// linear (tid*16B), source pre-swizzled.
//
// Phase p of a K-tile: P0=(kh0,ilo)+Bread, P1=(kh0,ihi), P2=(kh1,ilo)
// +Bread, P3=(kh1,ihi). Region free times: B-kh0 end-P0, A-kh0 end-P1,
// B-kh1 end-P2, A-kh1 end-P3. Stage schedule per iteration (tiles
// 2i->buf0 ph0-3, 2i+1->buf1 ph4-7), one half-tile (2 gload_lds/thr):
//   ph0:S(2i+1,A,kh1) ph1:S(2i+2,B,kh0) ph2:S(2i+2,A,kh0)
//   ph3:S(2i+2,B,kh1) ph4:S(2i+2,A,kh1) ph5:S(2i+3,B,kh0)
//   ph6:S(2i+3,A,kh0) ph7:S(2i+3,B,kh1)
// vmcnt(6) (3 half-tiles in flight) only before closing barriers of
// ph3/ph7: every read's stage is then >=4 stages old => landed.
// =====================================================================

#define BAR()    asm volatile("s_barrier" ::: "memory")
#define LGKM0()  asm volatile("s_waitcnt lgkmcnt(0)" ::: "memory")
#define VM6()    asm volatile("s_waitcnt vmcnt(6)" ::: "memory")
#define VM0()    asm volatile("s_waitcnt vmcnt(0)" ::: "memory")
#define SCHED0() __builtin_amdgcn_sched_barrier(0)

__global__ __launch_bounds__(512, 2) void gemm_fused(
    const u16* __restrict__ Wb,  // w1b [N_H][KPAD]
    const u16* __restrict__ Xb,  // xb  [M_B][KPAD]
    const float* __restrict__ b1,
    const signed char* __restrict__ W2c,  // [N_H][16]
    float* __restrict__ plog)    // [M_B][16] fp32, atomicAdd target
{
    __shared__ __align__(128) u16 lds[65536];   // 128 KB exactly

    const int tid  = threadIdx.x;
    const int lane = tid & 63;
    const int wave = tid >> 6;
    const int wr = wave >> 2;           // j-half of block (0..1)
    const int wc = wave & 3;            // b-quarter of block (0..3)

    // XCD-aware swizzle: 512 blocks, 64/XCD chunk; bm fastest -> B reuse
    const int bid = blockIdx.x;
    const int swz = (bid & 7) * 64 + (bid >> 3);
    const int bm = swz & 15;            // 16 j-tiles of 256
    const int bn = swz >> 4;            // 32 b-tiles of 256

    // ---- stage source pointers (pre-swizzled k-chunk) ----
    // slot s = tid + 512q: row = (tid>>2)+128q, c2 = tid&3,
    // co = c2 ^ ((row>>1)&3)  (q-invariant since 128q>>1 is mult of 4)
    const int srow = tid >> 2;
    const int co   = (tid & 3) ^ ((srow >> 1) & 3);
    const u16* gA0 = Wb + (size_t)(bm * 256 + srow) * KPAD + co * 8;
    const u16* gA1 = gA0 + (size_t)128 * KPAD;
    const u16* gB0 = Xb + (size_t)(bn * 256 + srow) * KPAD + co * 8;
    const u16* gB1 = gB0 + (size_t)128 * KPAD;

    // ---- fragment read bases (u16 units): row*32 + (q'^lg)*8 ----
    const int lm    = lane & 15;
    const int aLane = lm * 32 + ((((lane >> 4) ^ (lm >> 1)) & 3) << 3);
    const int aBase = wr * 4096 + aLane;            // A: + (wr*128 rows)*32
    const int bBase = 32768 + wc * 2048 + aLane;    // B op + (wc*64 rows)*32

    f32x4 acc[8][4] = {};   // acc[i = j 16-block (0..7)][jb = b 16-block]
    bf16x8 bfr[4];          // B frags, live across 2 phases

#define STAGE(SOP, SP0, SP1, ST, SKH)                                      \
    if ((ST) < TILES) {                                                    \
      const int rb = (SOP)*32768 + ((ST)&1)*16384 + (SKH)*8192 + tid*8;    \
      load_lds16(SP0 + (ST)*64 + (SKH)*32, lds + rb);                      \
      load_lds16(SP1 + (ST)*64 + (SKH)*32, lds + rb + 4096);               \
    }

#define RD_A(BUF, KH, IH)                                                  \
    { const u16* pa = lds + aBase + ((BUF)*16384 + (KH)*8192 + (IH)*2048); \
      af[0] = *(const bf16x8*)(pa);                                        \
      af[1] = *(const bf16x8*)(pa + 512);                                  \
      af[2] = *(const bf16x8*)(pa + 1024);                                 \
      af[3] = *(const bf16x8*)(pa + 1536); }

#define RD_B(BUF, KH)                                                      \
    { const u16* pb = lds + bBase + ((BUF)*16384 + (KH)*8192);             \
      bfr[0] = *(const bf16x8*)(pb);                                       \
      bfr[1] = *(const bf16x8*)(pb + 512);                                 \
      bfr[2] = *(const bf16x8*)(pb + 1024);                                \
      bfr[3] = *(const bf16x8*)(pb + 1536); }

#define MFMA16(IH)                                                         \
    __builtin_amdgcn_s_setprio(1);                                         \
    _Pragma("unroll")                                                      \
    for (int ii = 0; ii < 4; ++ii)                                         \
      _Pragma("unroll")                                                    \
      for (int jb = 0; jb < 4; ++jb)                                       \
        acc[(IH)*4 + ii][jb] = __builtin_amdgcn_mfma_f32_16x16x32_bf16(    \
            af[ii], bfr[jb], acc[(IH)*4 + ii][jb], 0, 0, 0);               \
    __builtin_amdgcn_s_setprio(0);

    // ---- prologue: tile0 all 4 halves, then tile1's first 3 ----
    STAGE(0, gA0, gA1, 0, 0);
    STAGE(1, gB0, gB1, 0, 0);
    STAGE(0, gA0, gA1, 0, 1);
    STAGE(1, gB0, gB1, 0, 1);
    STAGE(1, gB0, gB1, 1, 0);
    STAGE(0, gA0, gA1, 1, 0);
    STAGE(1, gB0, gB1, 1, 1);
    VM6(); BAR();

    // ---- main loop: 6 iterations x 2 K-tiles ----
    #pragma unroll 1
    for (int i = 0; i < 6; ++i) {
        const int t1 = 2 * i + 1, t2 = 2 * i + 2, t3 = 2 * i + 3;
        { bf16x8 af[4]; RD_A(0,0,0); RD_B(0,0); STAGE(0, gA0, gA1, t1, 1);
          BAR(); LGKM0(); SCHED0(); MFMA16(0); } BAR();
        { bf16x8 af[4]; RD_A(0,0,1);            STAGE(1, gB0, gB1, t2, 0);
          BAR(); LGKM0(); SCHED0(); MFMA16(1); } BAR();
        { bf16x8 af[4]; RD_A(0,1,0); RD_B(0,1); STAGE(0, gA0, gA1, t2, 0);
          BAR(); LGKM0(); SCHED0(); MFMA16(0); } BAR();
        { bf16x8 af[4]; RD_A(0,1,1);            STAGE(1, gB0, gB1, t2, 1);
          BAR(); LGKM0(); SCHED0(); MFMA16(1); } VM6(); BAR();
        { bf16x8 af[4]; RD_A(1,0,0); RD_B(1,0); STAGE(0, gA0, gA1, t2, 1);
          BAR(); LGKM0(); SCHED0(); MFMA16(0); } BAR();
        { bf16x8 af[4]; RD_A(1,0,1);            STAGE(1, gB0, gB1, t3, 0);
          BAR(); LGKM0(); SCHED0(); MFMA16(1); } BAR();
        { bf16x8 af[4]; RD_A(1,1,0); RD_B(1,1); STAGE(0, gA0, gA1, t3, 0);
          BAR(); LGKM0(); SCHED0(); MFMA16(0); } BAR();
        { bf16x8 af[4]; RD_A(1,1,1);            STAGE(1, gB0, gB1, t3, 1);
          BAR(); LGKM0(); SCHED0(); MFMA16(1); } VM6(); BAR();
    }

    // ---- drain + last K-tile (tile 12, buf0), no staging ----
    VM0(); BAR();
    { bf16x8 af[4]; RD_A(0,0,0); RD_B(0,0); MFMA16(0); }
    { bf16x8 af[4]; RD_A(0,0,1);            MFMA16(1); }
    { bf16x8 af[4]; RD_A(0,1,0); RD_B(0,1); MFMA16(0); }
    { bf16x8 af[4]; RD_A(0,1,1);            MFMA16(1); }

    // ---- fused epilogue: h = relu(acc + b1[j]); plog[b][o] += h * w2 ----
    const int quad = lane >> 4;
    const int o = lm;
    const int jrow = bm * 256 + wr * 128 + quad * 4;   // + ii*16 + jj

    bf16x8 wf[8];
    #pragma unroll
    for (int ii = 0; ii < 8; ++ii) {
        #pragma unroll
        for (int jj = 0; jj < 4; ++jj) {
            signed char s8 = W2c[(size_t)(jrow + ii * 16 + jj) * 16 + o];
            wf[ii][jj] = (s8 == 0) ? (short)0
                                   : (s8 > 0 ? (short)0x3F80 : (short)0xBF80);
            wf[ii][jj + 4] = 0;
        }
    }
    float4 bias[8];
    #pragma unroll
    for (int ii = 0; ii < 8; ++ii)
        bias[ii] = *(const float4*)(b1 + jrow + ii * 16);

    f32x4 d2[4] = {};   // d2[jb]: col = o, row = b-local = quad*4 + r
    #pragma unroll
    for (int jb = 0; jb < 4; ++jb) {
        #pragma unroll
        for (int ii = 0; ii < 8; ++ii) {
            bf16x8 hf;
            const float* bi = (const float*)&bias[ii];
            #pragma unroll
            for (int r = 0; r < 4; ++r) {
                float v = fmaxf(acc[ii][jb][r] + bi[r], 0.f);
                hf[r] = (short)f2bf(v);
                hf[r + 4] = 0;
            }
            d2[jb] = __builtin_amdgcn_mfma_f32_16x16x32_bf16(hf, wf[ii], d2[jb], 0, 0, 0);
        }
    }

    if (o < N_OUT) {
        #pragma unroll
        for (int jb = 0; jb < 4; ++jb) {
            const int bbase = bn * 256 + wc * 64 + jb * 16 + quad * 4;
            #pragma unroll
            for (int r = 0; r < 4; ++r)
                atomicAdd(&plog[(size_t)(bbase + r) * 16 + o], d2[jb][r]);
        }
    }
}

// ---- + b2, log_softmax; one thread per batch row ----
__global__ __launch_bounds__(128) void lsm_out(
    const float* __restrict__ plog,
    const float* __restrict__ b2,
    float* __restrict__ out)
{
    const int b = blockIdx.x * 128 + threadIdx.x;

    float4 p0 = *(const float4*)(plog + (size_t)b * 16);
    float4 p1 = *(const float4*)(plog + (size_t)b * 16 + 4);
    float4 p2 = *(const float4*)(plog + (size_t)b * 16 + 8);
    float p[10] = {p0.x, p0.y, p0.z, p0.w, p1.x, p1.y, p1.z, p1.w, p2.x, p2.y};

    float lg[N_OUT], mx = -1e30f;
    #pragma unroll
    for (int o = 0; o < N_OUT; ++o) {
        lg[o] = p[o] + b2[o];
        mx = fmaxf(mx, lg[o]);
    }
    float se = 0.f;
    #pragma unroll
    for (int o = 0; o < N_OUT; ++o) se += expf(lg[o] - mx);
    const float lse = logf(se) + mx;
    float* op = out + (size_t)b * N_OUT;
    #pragma unroll
    for (int o = 0; o < N_OUT; ++o) op[o] = lg[o] - lse;
}

extern "C" void kernel_launch(void* const* d_in, const int* in_sizes, int n_in,
                              void* d_out, int out_size, void* d_ws, size_t ws_size,
                              hipStream_t stream) {
    const float* x  = (const float*)d_in[0];
    const float* w1 = (const float*)d_in[1];
    const float* b1 = (const float*)d_in[2];
    const float* w2 = (const float*)d_in[3];
    const float* b2 = (const float*)d_in[4];
    float* out = (float*)d_out;

    // ws carve (KPAD=832): total ~21.0 MB
    char* ws = (char*)d_ws;
    u16* xb  = (u16*)(ws);                            // 13,631,488 B
    u16* w1b = (u16*)(ws + 13631488);                 //  6,815,744 B
    signed char* w2c = (signed char*)(ws + 20447232); //     65,536 B
    float* plog = (float*)(ws + 20512768);            //    524,288 B

    prep_all<<<5136, 256, 0, stream>>>(x, w1, w2, xb, w1b, w2c, plog);
    gemm_fused<<<512, 512, 0, stream>>>(w1b, xb, b1, w2c, plog);
    lsm_out<<<64, 128, 0, stream>>>(plog, b2, out);
}